// Round 7
// baseline (134.610 us; speedup 1.0000x reference)
//
#include <hip/hip_runtime.h>

typedef float v2f __attribute__((ext_vector_type(2)));
typedef float v4f __attribute__((ext_vector_type(4)));

#define IMG 512
#define TSX 32
#define TSY 16
#define NBLK 4096             // 16 x 32 tiles x 8 images, 1 tile per block

// LDS layouts (floats)
#define A_STR  60             // h tile [36][60]; gy=y0-10+r, gx=x0-12+c (cols 0..55)
#define BT_STR 28             // BT [56][28]: BT[c][by], by 0..25 (gy=y0-5+by)
#define E_STR  64             // E [26][64] XOR-swizzled; overlays Abuf
#define CT_STR 18             // CT [42][18]: CT[ex][oy], oy 0..15; overlays Bbuf
#define C_STR  49             // c tile [26][49]; gy=y0-5+r, gx=x0-8+cc (ex -> cc=ex+3)

__device__ __forceinline__ v2f lo2(v4f v) { return __builtin_shufflevector(v, v, 0, 1); }
__device__ __forceinline__ v2f hi2(v4f v) { return __builtin_shufflevector(v, v, 2, 3); }

// one float4 of the h halo tile (zero-padded), quad idx in [0,504): 36 rows x 14 quads
__device__ __forceinline__ v4f ldq(const float* __restrict__ hmap, size_t base,
                                   int x0, int y0, int idx) {
    int r = idx / 14, q = idx - r * 14;
    int gy = y0 - 10 + r, gx0 = x0 - 12 + 4 * q;
    v4f v = {0.f, 0.f, 0.f, 0.f};
    if ((unsigned)gy < IMG) {
        const float* hr = &hmap[base + ((size_t)gy << 9)];
        if (gx0 >= 0 && gx0 + 3 < IMG) {
            v = *(const v4f*)&hr[gx0];
        } else {
            if ((unsigned)(gx0 + 0) < IMG) v.x = hr[gx0 + 0];
            if ((unsigned)(gx0 + 1) < IMG) v.y = hr[gx0 + 1];
            if ((unsigned)(gx0 + 2) < IMG) v.z = hr[gx0 + 2];
            if ((unsigned)(gx0 + 3) < IMG) v.w = hr[gx0 + 3];
        }
    }
    return v;
}

// one float4 of the c tile (zero-padded), quad idx in [0,312): 26 rows x 12 quads
__device__ __forceinline__ v4f ldc(const float* __restrict__ cmap, size_t base,
                                   int x0, int y0, int idx) {
    int r = idx / 12, q = idx - r * 12;
    int gy = y0 - 5 + r, gx0 = x0 - 8 + 4 * q;
    v4f v = {0.f, 0.f, 0.f, 0.f};
    if ((unsigned)gy < IMG) {
        const float* cr = &cmap[base + ((size_t)gy << 9)];
        if (gx0 >= 0 && gx0 + 3 < IMG) {
            v = *(const v4f*)&cr[gx0];
        } else {
            if ((unsigned)(gx0 + 0) < IMG) v.x = cr[gx0 + 0];
            if ((unsigned)(gx0 + 1) < IMG) v.y = cr[gx0 + 1];
            if ((unsigned)(gx0 + 2) < IMG) v.z = cr[gx0 + 2];
            if ((unsigned)(gx0 + 3) < IMG) v.w = cr[gx0 + 3];
        }
    }
    return v;
}

__global__ __launch_bounds__(256, 8) void marl_fused(
    const float* __restrict__ prob,
    const float* __restrict__ cmap,
    const float* __restrict__ hmap,
    float* __restrict__ out)
{
    __shared__ __align__(16) float Abuf[36 * A_STR];   // 2160 f: h tile, then E[26][64]
    __shared__ __align__(16) float Bbuf[56 * BT_STR];  // 1568 f: BT, then CT[42][18]
    __shared__ __align__(16) float Cbuf[26 * C_STR];   // 1274 f: c tile
    __shared__ float red[4];

    const float W[11] = {0.00881223f, 0.02714358f, 0.06511405f, 0.12164908f,
                         0.17699840f, 0.20056540f, 0.17699840f, 0.12164908f,
                         0.06511405f, 0.02714358f, 0.00881223f};
    v2f wv[11];
#pragma unroll
    for (int i = 0; i < 11; ++i) wv[i] = (v2f){W[i], W[i]};
    float w2 = 0.f;
#pragma unroll
    for (int i = 0; i < 11; ++i) w2 += W[i] * W[i];
    const float sumk2 = w2 * w2;
    const v2f z = {0.f, 0.f};

    const int tid = threadIdx.x;
    // tile decode: 512 tiles/image (16 x, 32 y)
    const int T  = blockIdx.x;
    const int b  = T >> 9, r9 = T & 511;
    const int x0 = (r9 & 15) * TSX, y0 = (r9 >> 4) * TSY;
    const size_t base = (size_t)b << 18;

    // P4 worker mapping (tid<128): oxp = tid>>3, p = tid&7
    const int ox0 = 2 * (tid >> 3), oy0e = 2 * (tid & 7);

    // ---- prologue: stage h + c; prefetch epilogue h/prob pairs ----
    v2f hv[2], pv[2];
    {
        v4f ha = ldq(hmap, base, x0, y0, tid);
        v4f hb = (tid < 248) ? ldq(hmap, base, x0, y0, tid + 256) : (v4f){0.f,0.f,0.f,0.f};
        v4f ca = ldc(cmap, base, x0, y0, tid);
        v4f cb = (tid < 56) ? ldc(cmap, base, x0, y0, tid + 256) : (v4f){0.f,0.f,0.f,0.f};
        if (tid < 128) {
#pragma unroll
            for (int h = 0; h < 2; ++h) {
                size_t rowb = base + ((size_t)(y0 + oy0e + h) << 9) + (x0 + ox0);
                hv[h] = *(const v2f*)&hmap[rowb];
                pv[h] = *(const v2f*)&prob[rowb];
            }
        }
        { int r = tid / 14, q = tid - r * 14; *(v4f*)&Abuf[r * A_STR + 4 * q] = ha; }
        if (tid < 248) { int i = tid + 256, r = i / 14, q = i - r * 14;
                         *(v4f*)&Abuf[r * A_STR + 4 * q] = hb; }
        { int r = tid / 12, q = tid - r * 12; float* d = &Cbuf[r * C_STR + 4 * q];
          d[0] = ca.x; d[1] = ca.y; d[2] = ca.z; d[3] = ca.w; }
        if (tid < 56) { int i = tid + 256, r = i / 12, q = i - r * 12;
                        float* d = &Cbuf[r * C_STR + 4 * q];
                        d[0] = cb.x; d[1] = cb.y; d[2] = cb.z; d[3] = cb.w; }
    }
    __syncthreads();

    // ---- P1: convY(h): Abuf[36][60] -> BT[56][28] (transposed) ----
    // 126 workers: q = tid/9 (col quad), run = tid%9 (by-triple); by = 3*run+r
    if (tid < 126) {
        int q = tid / 9, run = tid - 9 * q;
        int by0 = 3 * run;
        v2f accLo[3] = {z, z, z}, accHi[3] = {z, z, z};
#pragma unroll
        for (int i = 0; i < 13; ++i) {
            v4f a = *(const v4f*)&Abuf[(by0 + i) * A_STR + 4 * q];
            v2f lo = lo2(a), hi = hi2(a);
#pragma unroll
            for (int r = 0; r < 3; ++r) {
                int j = i - r;
                if (j >= 0 && j < 11) { accLo[r] += wv[j] * lo; accHi[r] += wv[j] * hi; }
            }
        }
#pragma unroll
        for (int r = 0; r < 3; ++r) {
            int by = by0 + r;
            if (by < 26) {
                Bbuf[(4 * q + 0) * BT_STR + by] = accLo[r].x;
                Bbuf[(4 * q + 1) * BT_STR + by] = accLo[r].y;
                Bbuf[(4 * q + 2) * BT_STR + by] = accHi[r].x;
                Bbuf[(4 * q + 3) * BT_STR + by] = accHi[r].y;
            }
        }
    }
    __syncthreads();

    // ---- P2: convX(BT) - c(LDS) -> E[26][64] swizzled (overlays Abuf) ----
    // 143 workers: eq = tid/13 (ex quad 0..10), p = tid%13 (ey pair)
    if (tid < 143) {
        int eq = tid / 13, p = tid - 13 * eq;
        int ex0 = 4 * eq, ey0 = 2 * p;
        v2f acc[4] = {z, z, z, z};
#pragma unroll
        for (int i = 0; i < 14; ++i) {
            v2f bb = *(const v2f*)&Bbuf[(ex0 + 2 + i) * BT_STR + ey0];
#pragma unroll
            for (int c = 0; c < 4; ++c) {
                int j = i - c;
                if (j >= 0 && j < 11) acc[c] += wv[j] * bb;
            }
        }
        int swz = (p & 7) << 2;   // == ((ey>>1)&7)<<2 for ey = 2p, 2p+1
#pragma unroll
        for (int c = 0; c < 4; ++c) {
            int ex = ex0 + c;
            if (ex < 42) {
                int gx = x0 - 5 + ex;
                bool xin = (unsigned)gx < IMG;
#pragma unroll
                for (int h = 0; h < 2; ++h) {
                    int gy = y0 - 5 + ey0 + h;
                    float v = 0.f;
                    if (xin && (unsigned)gy < IMG)
                        v = acc[c][h] - Cbuf[(ey0 + h) * C_STR + ex + 3];
                    Abuf[(ey0 + h) * E_STR + (ex ^ swz)] = v;
                }
            }
        }
    }
    __syncthreads();

    // ---- P3: convY(E) -> CT[42][18] (transposed, overlays Bbuf) ----
    // 88 workers: eq = tid/8 (ex quad 0..10), run = tid%8 (oy pair)
    if (tid < 88) {
        int eq = tid >> 3, run = tid & 7;
        int ex0 = 4 * eq, oy0 = 2 * run;
        v2f accLo[2] = {z, z}, accHi[2] = {z, z};
#pragma unroll
        for (int i = 0; i < 12; ++i) {
            int row = oy0 + i;
            v4f e = *(const v4f*)&Abuf[row * E_STR + (ex0 ^ (((row >> 1) & 7) << 2))];
            v2f lo = lo2(e), hi = hi2(e);
#pragma unroll
            for (int r = 0; r < 2; ++r) {
                int j = i - r;
                if (j >= 0 && j < 11) { accLo[r] += wv[j] * lo; accHi[r] += wv[j] * hi; }
            }
        }
#pragma unroll
        for (int r = 0; r < 2; ++r) {
            int oy = oy0 + r;
            Bbuf[(ex0 + 0) * CT_STR + oy] = accLo[r].x;
            Bbuf[(ex0 + 1) * CT_STR + oy] = accLo[r].y;
            if (ex0 + 2 < 42) {
                Bbuf[(ex0 + 2) * CT_STR + oy] = accHi[r].x;
                Bbuf[(ex0 + 3) * CT_STR + oy] = accHi[r].y;
            }
        }
    }
    __syncthreads();

    // ---- P4: convX(CT) -> corr + fused epilogue (128 workers) ----
    float partial = 0.f;
    if (tid < 128) {
        v2f acc[2] = {z, z};
#pragma unroll
        for (int i = 0; i < 12; ++i) {
            v2f ct = *(const v2f*)&Bbuf[(ox0 + i) * CT_STR + oy0e];
#pragma unroll
            for (int c = 0; c < 2; ++c) {
                int j = i - c;
                if (j >= 0 && j < 11) acc[c] += wv[j] * ct;
            }
        }
#pragma unroll
        for (int h = 0; h < 2; ++h) {
#pragma unroll
            for (int c = 0; c < 2; ++c) {
                float h_ = hv[h][c], p_ = pv[h][c];
                float logp = __logf(h_ > 0.5f ? p_ + 1e-8f : 1.f - p_ + 1e-8f);
                float delta = 1.f - 2.f * h_;
                partial += (2.f * delta * acc[c][h] + sumk2) * logp;
            }
        }
    }

    // ---- reduction + one atomic per block ----
#pragma unroll
    for (int off = 32; off > 0; off >>= 1)
        partial += __shfl_down(partial, off, 64);
    if ((tid & 63) == 0) red[tid >> 6] = partial;
    __syncthreads();
    if (tid == 0) {
        float s = red[0] + red[1] + red[2] + red[3];
        atomicAdd(out, s * -0.125f);   // loss = -sum / B
    }
}

extern "C" void kernel_launch(void* const* d_in, const int* in_sizes, int n_in,
                              void* d_out, int out_size, void* d_ws, size_t ws_size,
                              hipStream_t stream) {
    const float* prob = (const float*)d_in[0];
    const float* cmap = (const float*)d_in[1];
    const float* hmap = (const float*)d_in[2];
    float* out = (float*)d_out;

    hipMemsetAsync(out, 0, sizeof(float), stream);

    marl_fused<<<dim3(NBLK), dim3(256), 0, stream>>>(prob, cmap, hmap, out);
}

// Round 8
// 91.067 us; speedup vs baseline: 1.4781x; 1.4781x over previous
//
#include <hip/hip_runtime.h>

typedef float v2f __attribute__((ext_vector_type(2)));
typedef float v4f __attribute__((ext_vector_type(4)));

#define IMG 512
#define TS  32
#define TPB 2                 // tiles per block
#define NBLK 1024             // 2048 tiles / 2

// LDS layouts (floats)
#define A_STR  58             // h tile [52][58]; gy=y0-10+r, gx=x0-12+c (cols 0..55)
#define BT_STR 46             // BT [56][46]: BT[c][by], by 0..41 (gy=y0-5+by)
#define ET_STR 44             // ET [42][44]: ET[ex][ey] (transposed E); overlays Abuf
#define CT_STR 36             // CT [42][36]: CT[ex][oy], oy 0..31; overlays Bbuf

__device__ __forceinline__ v2f lo2(v4f v) { return __builtin_shufflevector(v, v, 0, 1); }
__device__ __forceinline__ v2f hi2(v4f v) { return __builtin_shufflevector(v, v, 2, 3); }

// one float4 of the h halo tile (zero-padded), quad index idx in [0,728)
__device__ __forceinline__ v4f ldq(const float* __restrict__ hmap, size_t base,
                                   int x0, int y0, int idx) {
    int r = idx / 14, q = idx - r * 14;
    int gy = y0 - 10 + r, gx0 = x0 - 12 + 4 * q;
    v4f v = {0.f, 0.f, 0.f, 0.f};
    if ((unsigned)gy < IMG) {
        const float* hr = &hmap[base + ((size_t)gy << 9)];
        if (gx0 >= 0 && gx0 + 3 < IMG) {
            v = *(const v4f*)&hr[gx0];
        } else {
            if ((unsigned)(gx0 + 0) < IMG) v.x = hr[gx0 + 0];
            if ((unsigned)(gx0 + 1) < IMG) v.y = hr[gx0 + 1];
            if ((unsigned)(gx0 + 2) < IMG) v.z = hr[gx0 + 2];
            if ((unsigned)(gx0 + 3) < IMG) v.w = hr[gx0 + 3];
        }
    }
    return v;
}

__global__ __launch_bounds__(256, 4) void marl_fused(
    const float* __restrict__ prob,
    const float* __restrict__ cmap,
    const float* __restrict__ hmap,
    float* __restrict__ out)
{
    __shared__ __align__(16) float Abuf[52 * A_STR];   // 3016 f: h tile, then ET[42][44]
    __shared__ __align__(16) float Bbuf[56 * BT_STR];  // 2576 f: BT, then CT[42][36]
    __shared__ float red[4];

    const float W[11] = {0.00881223f, 0.02714358f, 0.06511405f, 0.12164908f,
                         0.17699840f, 0.20056540f, 0.17699840f, 0.12164908f,
                         0.06511405f, 0.02714358f, 0.00881223f};
    v2f wv[11];
#pragma unroll
    for (int i = 0; i < 11; ++i) wv[i] = (v2f){W[i], W[i]};
    float w2 = 0.f;
#pragma unroll
    for (int i = 0; i < 11; ++i) w2 += W[i] * W[i];
    const float sumk2 = w2 * w2;
    const v2f z = {0.f, 0.f};

    const int tid = threadIdx.x;
    const int i0 = tid, i1 = tid + 256, i2 = tid + 512;
    const int T0 = blockIdx.x * TPB;

    // P1 mapping: 98 workers (tid<98), run fastest (LDS-write-friendly)
    const int p1run = tid % 7, p1q = tid / 7;         // by0 = 6*p1run, cols 4*p1q
    // P2 mapping: 231 workers (tid<231): p = ey-pair, eq = ex-quad
    const int p2p = tid % 21, p2eq = tid / 21;        // ey0 = 2*p2p, ex0 = 4*p2eq
    // P3 mapping: 168 workers (tid<168): oyq fastest, then ex
    const int p3oyq = tid & 3, p3ex = tid >> 2;       // oy0 = 8*p3oyq
    // P4 mapping: all 256: lanes vary oy-pair (CT read stride 2 -> free)
    const int oy0e = 2 * (tid & 15), ox0 = 2 * (tid >> 4);

    v2f hv[TPB][2], pv[TPB][2];
    float creg[TPB][2][4];   // P2 workers' c values (2 rows x 4 cols), static idx

    // ---- prologue: tile 0 — stage h to LDS; c + epilogue h/prob to regs ----
    {
        const int b = T0 >> 8, r8 = T0 & 255;
        const int x0 = (r8 & 15) * TS, y0 = (r8 >> 4) * TS;
        const size_t base = (size_t)b << 18;
        v4f ha = ldq(hmap, base, x0, y0, i0);
        v4f hb = ldq(hmap, base, x0, y0, i1);
        v4f hc = (tid < 216) ? ldq(hmap, base, x0, y0, i2) : (v4f){0.f,0.f,0.f,0.f};
        if (tid < 231) {
#pragma unroll
            for (int h = 0; h < 2; ++h) {
                int gy = y0 - 5 + 2 * p2p + h;
#pragma unroll
                for (int c = 0; c < 4; ++c) {
                    int gx = x0 - 5 + 4 * p2eq + c;
                    creg[0][h][c] = ((unsigned)gy < IMG && (unsigned)gx < IMG)
                        ? cmap[base + ((size_t)gy << 9) + gx] : 0.f;
                }
            }
        }
#pragma unroll
        for (int h = 0; h < 2; ++h) {
            size_t rowb = base + ((size_t)(y0 + oy0e + h) << 9) + (x0 + ox0);
            hv[0][h] = *(const v2f*)&hmap[rowb];
            pv[0][h] = *(const v2f*)&prob[rowb];
        }
        { int r = i0 / 14, q = i0 - r * 14; *(v4f*)&Abuf[r * A_STR + 4 * q] = ha; }
        { int r = i1 / 14, q = i1 - r * 14; *(v4f*)&Abuf[r * A_STR + 4 * q] = hb; }
        if (tid < 216) { int r = i2 / 14, q = i2 - r * 14; *(v4f*)&Abuf[r * A_STR + 4 * q] = hc; }
    }
    __syncthreads();

    float partial = 0.f;
    v4f pfh0, pfh1, pfh2;

#pragma unroll
    for (int t = 0; t < TPB; ++t) {
        const int T = T0 + t;
        const int r8 = T & 255;
        const int x0 = (r8 & 15) * TS, y0 = (r8 >> 4) * TS;

        // ---- P1: convY(h): Abuf[52][58] -> BT[56][46], 6 outs/worker ----
        if (tid < 98) {
            int by0 = 6 * p1run;
            v2f accLo[6] = {z, z, z, z, z, z}, accHi[6] = {z, z, z, z, z, z};
#pragma unroll
            for (int i = 0; i < 16; ++i) {
                v4f a = *(const v4f*)&Abuf[(by0 + i) * A_STR + 4 * p1q];
                v2f lo = lo2(a), hi = hi2(a);
#pragma unroll
                for (int r = 0; r < 6; ++r) {
                    int j = i - r;
                    if (j >= 0 && j < 11) { accLo[r] += wv[j] * lo; accHi[r] += wv[j] * hi; }
                }
            }
#pragma unroll
            for (int r = 0; r < 6; ++r) {
                int by = by0 + r;
                Bbuf[(4 * p1q + 0) * BT_STR + by] = accLo[r].x;
                Bbuf[(4 * p1q + 1) * BT_STR + by] = accLo[r].y;
                Bbuf[(4 * p1q + 2) * BT_STR + by] = accHi[r].x;
                Bbuf[(4 * p1q + 3) * BT_STR + by] = accHi[r].y;
            }
        }
        __syncthreads();

        // ---- P2: convX(BT) - c(regs) -> ET[42][44] transposed (overlays Abuf) ----
        if (tid < 231) {
            int ex0 = 4 * p2eq, ey0 = 2 * p2p;
            v2f acc[4] = {z, z, z, z};
#pragma unroll
            for (int i = 0; i < 14; ++i) {
                v2f bb = *(const v2f*)&Bbuf[(ex0 + 2 + i) * BT_STR + ey0];
#pragma unroll
                for (int c = 0; c < 4; ++c) {
                    int j = i - c;
                    if (j >= 0 && j < 11) acc[c] += wv[j] * bb;
                }
            }
#pragma unroll
            for (int c = 0; c < 4; ++c) {
                int ex = ex0 + c;
                if (ex < 42) {
                    int gx = x0 - 5 + ex;
                    bool xin = (unsigned)gx < IMG;
#pragma unroll
                    for (int h = 0; h < 2; ++h) {
                        int gy = y0 - 5 + ey0 + h;
                        float v = 0.f;
                        if (xin && (unsigned)gy < IMG)
                            v = acc[c][h] - creg[t][h][c];
                        Abuf[ex * ET_STR + ey0 + h] = v;
                    }
                }
            }
        }
        __syncthreads();

        // ---- P3: prefetch next tile; convY(ET) via register window -> CT ----
        if (t + 1 < TPB) {
            const int Tn = T + 1;
            const int nb = Tn >> 8, nr8 = Tn & 255;
            const int nx0 = (nr8 & 15) * TS, ny0 = (nr8 >> 4) * TS;
            const size_t nbase = (size_t)nb << 18;
            pfh0 = ldq(hmap, nbase, nx0, ny0, i0);
            pfh1 = ldq(hmap, nbase, nx0, ny0, i1);
            if (tid < 216) pfh2 = ldq(hmap, nbase, nx0, ny0, i2);
            if (tid < 231) {
#pragma unroll
                for (int h = 0; h < 2; ++h) {
                    int gy = ny0 - 5 + 2 * p2p + h;
#pragma unroll
                    for (int c = 0; c < 4; ++c) {
                        int gx = nx0 - 5 + 4 * p2eq + c;
                        creg[t + 1][h][c] = ((unsigned)gy < IMG && (unsigned)gx < IMG)
                            ? cmap[nbase + ((size_t)gy << 9) + gx] : 0.f;
                    }
                }
            }
#pragma unroll
            for (int h = 0; h < 2; ++h) {
                size_t rowb = nbase + ((size_t)(ny0 + oy0e + h) << 9) + (nx0 + ox0);
                hv[t + 1][h] = *(const v2f*)&hmap[rowb];
                pv[t + 1][h] = *(const v2f*)&prob[rowb];
            }
        }
        if (tid < 168) {
            int oy0 = 8 * p3oyq;
            const float* src = &Abuf[p3ex * ET_STR + oy0];
            v4f w0 = *(const v4f*)&src[0];
            v4f w1 = *(const v4f*)&src[4];
            v4f w2_ = *(const v4f*)&src[8];
            v4f w3 = *(const v4f*)&src[12];
            v4f w4 = *(const v4f*)&src[16];
            float win[20];
            *(v4f*)&win[0] = w0; *(v4f*)&win[4] = w1; *(v4f*)&win[8] = w2_;
            *(v4f*)&win[12] = w3; *(v4f*)&win[16] = w4;
            float o[8];
#pragma unroll
            for (int k = 0; k < 8; ++k) {
                float acc = 0.f;
#pragma unroll
                for (int j = 0; j < 11; ++j) acc += W[j] * win[k + j];
                o[k] = acc;
            }
            *(v4f*)&Bbuf[p3ex * CT_STR + oy0]     = (v4f){o[0], o[1], o[2], o[3]};
            *(v4f*)&Bbuf[p3ex * CT_STR + oy0 + 4] = (v4f){o[4], o[5], o[6], o[7]};
        }
        __syncthreads();

        // ---- P4: stage next h into Abuf; convX(CT) -> corr + epilogue ----
        if (t + 1 < TPB) {
            { int r = i0 / 14, q = i0 - r * 14; *(v4f*)&Abuf[r * A_STR + 4 * q] = pfh0; }
            { int r = i1 / 14, q = i1 - r * 14; *(v4f*)&Abuf[r * A_STR + 4 * q] = pfh1; }
            if (tid < 216) { int r = i2 / 14, q = i2 - r * 14; *(v4f*)&Abuf[r * A_STR + 4 * q] = pfh2; }
        }
        {
            v2f acc[2] = {z, z};
#pragma unroll
            for (int i = 0; i < 12; ++i) {
                v2f ct = *(const v2f*)&Bbuf[(ox0 + i) * CT_STR + oy0e];
#pragma unroll
                for (int c = 0; c < 2; ++c) {
                    int j = i - c;
                    if (j >= 0 && j < 11) acc[c] += wv[j] * ct;
                }
            }
#pragma unroll
            for (int h = 0; h < 2; ++h) {
#pragma unroll
                for (int c = 0; c < 2; ++c) {
                    float h_ = hv[t][h][c], p_ = pv[t][h][c];
                    float logp = __logf(h_ > 0.5f ? p_ + 1e-8f : 1.f - p_ + 1e-8f);
                    float delta = 1.f - 2.f * h_;
                    partial += (2.f * delta * acc[c][h] + sumk2) * logp;
                }
            }
        }
        __syncthreads();
    }

    // ---- single reduction + one atomic per block ----
#pragma unroll
    for (int off = 32; off > 0; off >>= 1)
        partial += __shfl_down(partial, off, 64);
    if ((tid & 63) == 0) red[tid >> 6] = partial;
    __syncthreads();
    if (tid == 0) {
        float s = red[0] + red[1] + red[2] + red[3];
        atomicAdd(out, s * -0.125f);   // loss = -sum / B
    }
}

extern "C" void kernel_launch(void* const* d_in, const int* in_sizes, int n_in,
                              void* d_out, int out_size, void* d_ws, size_t ws_size,
                              hipStream_t stream) {
    const float* prob = (const float*)d_in[0];
    const float* cmap = (const float*)d_in[1];
    const float* hmap = (const float*)d_in[2];
    float* out = (float*)d_out;

    hipMemsetAsync(out, 0, sizeof(float), stream);

    marl_fused<<<dim3(NBLK), dim3(256), 0, stream>>>(prob, cmap, hmap, out);
}